// Round 19
// baseline (107.973 us; speedup 1.0000x reference)
//
#include <hip/hip_runtime.h>
#include <hip/hip_bf16.h>
#include <cstdint>

#define D_   256
#define E_   4096
#define NN_  2048

typedef float f32x4_t __attribute__((ext_vector_type(4)));
typedef short bf16x8_t __attribute__((ext_vector_type(8)));
typedef short bf16x4_t __attribute__((ext_vector_type(4)));

__device__ inline short f2bf(float f) {
    union { float fv; unsigned u; } v; v.fv = f;
    unsigned r = v.u + 0x7fffu + ((v.u >> 16) & 1u);
    return (short)(r >> 16);
}

__device__ inline unsigned cvtpk_bf16(float lo, float hi) {
    unsigned r;
    asm("v_cvt_pk_bf16_f32 %0, %1, %2" : "=v"(r) : "v"(lo), "v"(hi));
    return r;
}

// Raw hardware exp2: v_exp_f32 computes 2^x in one transcendental op.
// (exp2f() is the PRECISE OCML call — cost ~15us/attn, r13 lesson.)
__device__ inline float hw_exp2(float x) {
    float r;
    asm("v_exp_f32 %0, %1" : "=v"(r) : "v"(x));
    return r;
}

// bf16 weight buffer layout (elements):
#define WB1   0
#define WB2   196608
#define WIPW  262144
#define WOW   458752
#define WLIN  524288
#define WROOT 589824

// ---------------------------------------------------------------------------
// bf16 MFMA GEMM, BK=64 (r19). One 16x16 frag per wave (NFR=1, unified).
// BM=64: 1024 threads = 16 waves (wr=w>>2 0..3, wc=w&3 0..3) — S1/S2/S5 were
//        1 block/CU x 8 waves = 25% occupancy (latency-bound, r16 lesson);
//        16 waves doubles it. Staging 8B/thread/matrix. Bit-identical
//        numerics (per-frag MFMA K-order unchanged).
// BM=32: 512 threads = 8 waves (wr=w>>2 0..1, wc=w&3) — M=2048 stages.
// B is pre-converted bf16 (r18). ABF16: A bf16. OUT: 0=f32, 1=bf16 (cols<256
// scaled by qsc), 2=qkv split (cols<512 -> qkvb; 512.. -> vt transposed).
// SCATTER: f32 atomicAdd via ei1. HASADD: += addsrc (f32, exact).
// ---------------------------------------------------------------------------
template<int BM, int ACT, bool GATHER, bool SCATTER, bool HASADD, bool ABF16, int OUT>
__global__ __launch_bounds__(1024)
void mgemm_k(const void* __restrict__ A, const short* __restrict__ Bmb,
             const float* __restrict__ bias, const float* __restrict__ addsrc,
             void* __restrict__ C, short* __restrict__ vtb,
             int M, int N, int K,
             const int* __restrict__ ei0, const int* __restrict__ ei1,
             const float* __restrict__ x, const float* __restrict__ eattr,
             float qsc)
{
    constexpr int ASZ  = BM * 128;
    constexpr int BOFF = 2 * ASZ;
    __shared__ char lds[BOFF + 16384];
    const int tid = threadIdx.x;
    const int w = tid >> 6, l = tid & 63;
    const int g = l >> 4, ln = l & 15;
    const int wr = w >> 2, wc = w & 3;
    const int m0 = blockIdx.x * BM, n0 = blockIdx.y * 64;

    // staging geometry: BM=64 -> 1024 thr, 8B/thread; BM=32 -> 512 thr, 16B
    const int srow = (BM == 64) ? (tid >> 4) : (tid >> 3);
    const int sck  = (BM == 64) ? ((tid & 15) * 4) : ((tid & 7) * 8);
    const int sswz = (srow & 7) << 4;
    const bool doA = (BM == 64) || (tid < 256);
    int gi1 = 0, gi0 = 0;
    if (GATHER) { gi1 = ei1[m0 + srow]; gi0 = ei0[m0 + srow]; }

    f32x4_t acc = {0.f, 0.f, 0.f, 0.f};

    const int nt = K >> 6;
    float4 ga[2];
    bf16x8_t gab8; bf16x4_t gab4, gbb4;
    bf16x8_t gbb8;

    auto loadG = [&](int kk) {
        const int cb = kk + sck;
        if (doA) {
            if (ABF16) {
                if (BM == 64) gab4 = *(const bf16x4_t*)((const short*)A + (size_t)(m0 + srow) * K + cb);
                else          gab8 = *(const bf16x8_t*)((const short*)A + (size_t)(m0 + srow) * K + cb);
            } else {
                const float* src;
                if (GATHER) {
                    if (cb < 256)      src = x + (size_t)gi1 * 256 + cb;
                    else if (cb < 512) src = x + (size_t)gi0 * 256 + (cb - 256);
                    else               src = eattr + (size_t)(m0 + srow) * 256 + (cb - 512);
                } else {
                    src = (const float*)A + (size_t)(m0 + srow) * K + cb;
                }
                ga[0] = *(const float4*)src;
                if (BM == 32) ga[1] = *(const float4*)(src + 4);
            }
        }
        if (BM == 64) gbb4 = *(const bf16x4_t*)(Bmb + (size_t)(n0 + srow) * K + cb);
        else          gbb8 = *(const bf16x8_t*)(Bmb + (size_t)(n0 + srow) * K + cb);
    };
    auto writeS = [&](int buf) {
        const int off = (srow*128 + sck*2) ^ sswz;
        if (doA) {
            if (ABF16) {
                if (BM == 64) *(bf16x4_t*)(lds + buf*ASZ + off) = gab4;
                else          *(bf16x8_t*)(lds + buf*ASZ + off) = gab8;
            } else if (BM == 64) {
                uint2 pa;
                pa.x = cvtpk_bf16(ga[0].x, ga[0].y);
                pa.y = cvtpk_bf16(ga[0].z, ga[0].w);
                *(uint2*)(lds + buf*ASZ + off) = pa;
            } else {
                uint4 pa;
                pa.x = cvtpk_bf16(ga[0].x, ga[0].y); pa.y = cvtpk_bf16(ga[0].z, ga[0].w);
                pa.z = cvtpk_bf16(ga[1].x, ga[1].y); pa.w = cvtpk_bf16(ga[1].z, ga[1].w);
                *(uint4*)(lds + buf*ASZ + off) = pa;
            }
        }
        if (BM == 64) *(bf16x4_t*)(lds + BOFF + buf*8192 + off) = gbb4;
        else          *(bf16x8_t*)(lds + BOFF + buf*8192 + off) = gbb8;
    };

    loadG(0);
    writeS(0);
    __syncthreads();
    int cur = 0;
    for (int t = 0; t < nt; ++t) {
        if (t + 1 < nt) loadG((t + 1) << 6);
        #pragma unroll
        for (int kc = 0; kc < 2; kc++) {
            const int arow = wr*16 + ln;
            const bf16x8_t af = *(const bf16x8_t*)(lds + cur*ASZ +
                    ((arow*128 + kc*64 + g*16) ^ ((arow&7)<<4)));
            const int brow = wc*16 + ln;
            const bf16x8_t bfr = *(const bf16x8_t*)(lds + BOFF + cur*8192 +
                     ((brow*128 + kc*64 + g*16) ^ ((brow&7)<<4)));
            acc = __builtin_amdgcn_mfma_f32_16x16x32_bf16(af, bfr, acc, 0, 0, 0);
        }
        if (t + 1 < nt) writeS(cur ^ 1);
        __syncthreads();
        cur ^= 1;
    }

    {
        const int col = n0 + wc*16 + ln;
        const float bv = bias[col];
        const int row0 = m0 + wr*16 + g*4;
        float pv[4];
        #pragma unroll
        for (int r = 0; r < 4; r++) {
            float v = acc[r] + bv;
            if (ACT == 1) v = v > 0.f ? v : 0.2f * v;
            if (HASADD) v += addsrc[(size_t)(row0 + r) * N + col];
            pv[r] = v;
        }
        if (SCATTER) {
            #pragma unroll
            for (int r = 0; r < 4; r++)
                atomicAdd(&((float*)C)[(size_t)ei1[row0 + r] * 256 + col], pv[r]);
        } else if (OUT == 0) {
            #pragma unroll
            for (int r = 0; r < 4; r++)
                ((float*)C)[(size_t)(row0 + r) * N + col] = pv[r];
        } else if (OUT == 1) {
            #pragma unroll
            for (int r = 0; r < 4; r++)
                ((short*)C)[(size_t)(row0 + r) * N + col] =
                    f2bf((col < 256) ? pv[r] * qsc : pv[r]);
        } else {   // OUT == 2: qkv split
            if (col < 512) {
                #pragma unroll
                for (int r = 0; r < 4; r++)
                    ((short*)C)[(size_t)(row0 + r) * 768 + col] =
                        f2bf((col < 256) ? pv[r] * qsc : pv[r]);
            } else {
                const int hd = (col - 512) >> 5, d = (col - 512) & 31;
                bf16x4_t pk;
                #pragma unroll
                for (int r = 0; r < 4; r++) pk[r] = f2bf(pv[r]);
                *(bf16x4_t*)(vtb + (size_t)hd*131072 + (size_t)d*4096 + row0) = pk;
            }
        }
    }
}

// ---------------------------------------------------------------------------
// Prep (r18): mask bit-pack + aggr zero (0..2047); rootT->bf16 (2048..2063);
// weight f32->bf16 (2064..2351, RNE cvt_pk — bit-identical to per-step cvt).
// ---------------------------------------------------------------------------
__global__ __launch_bounds__(256)
void prep_k(const int* __restrict__ mraw, unsigned int* __restrict__ pm,
            const float* __restrict__ root,
            const float* __restrict__ W1, const float* __restrict__ W2,
            const float* __restrict__ ipw, const float* __restrict__ ow,
            const float* __restrict__ lnw,
            short* __restrict__ wbuf, float* __restrict__ aggr)
{
    __shared__ float T[64][65];
    const int bid = blockIdx.x;
    if (bid < 2048) {
        const int t = bid * 256 + threadIdx.x;
        aggr[t] = 0.f;
        const int row = t >> 7, wb = t & 127;
        unsigned int bits = 0;
        const uint4* p = (const uint4*)(mraw + (size_t)row * 4096 + wb * 32);
        #pragma unroll
        for (int g = 0; g < 8; g++) {
            const uint4 v = p[g];
            if (v.x) bits |= 1u << (g*4+0);
            if (v.y) bits |= 1u << (g*4+1);
            if (v.z) bits |= 1u << (g*4+2);
            if (v.w) bits |= 1u << (g*4+3);
        }
        pm[t] = bits;
    } else if (bid < 2064) {
        const int bt = bid - 2048;
        const int m0 = (bt >> 2) * 64, n0 = (bt & 3) * 64;
        const int r = threadIdx.x >> 6, c = threadIdx.x & 63;
        #pragma unroll
        for (int i = 0; i < 16; i++)
            T[r + i*4][c] = root[(size_t)(m0 + r + i*4) * 256 + n0 + c];
        __syncthreads();
        #pragma unroll
        for (int i = 0; i < 16; i++)
            wbuf[WROOT + (size_t)(n0 + r + i*4) * 256 + m0 + c] = f2bf(T[c][r + i*4]);
    } else {
        const int wid = bid - 2064;
        const float* src; int dst, lw;
        if (wid < 96)       { src = W1;  dst = WB1;  lw = wid; }
        else if (wid < 128) { src = W2;  dst = WB2;  lw = wid - 96; }
        else if (wid < 224) { src = ipw; dst = WIPW; lw = wid - 128; }
        else if (wid < 256) { src = ow;  dst = WOW;  lw = wid - 224; }
        else                { src = lnw; dst = WLIN; lw = wid - 256; }
        const int e0 = (lw * 256 + threadIdx.x) * 8;
        const float4 a = *(const float4*)(src + e0);
        const float4 b = *(const float4*)(src + e0 + 4);
        uint4 p;
        p.x = cvtpk_bf16(a.x, a.y); p.y = cvtpk_bf16(a.z, a.w);
        p.z = cvtpk_bf16(b.x, b.y); p.w = cvtpk_bf16(b.z, b.w);
        *(uint4*)(wbuf + dst + e0) = p;
    }
}

// ---------------------------------------------------------------------------
// MFMA bf16 flash attention (r18 validated 51.7us): swapped QK^T; fixed-shift
// base-2 softmax (q pre-scaled by log2e/sqrt(32), p = hw_exp2(s - 12*log2e));
// split-K x2 strided; dbuf K/V; setprio; mask prefetch; lsum via ones-MFMA;
// additive merge; bf16 output. DO NOT widen split-K (r9/r5 L2 collapse);
// exp2f is OCML (r13).
// ---------------------------------------------------------------------------
__global__ __launch_bounds__(512, 4)
void attn_k(const short* __restrict__ qkvb, const short* __restrict__ vt,
            const unsigned int* __restrict__ pmask, short* __restrict__ ob)
{
    __shared__ char lds[49152];
    const int tid = threadIdx.x;
    const int w2 = tid >> 6, l = tid & 63;
    const int g = l >> 4, ln = l & 15;
    const int gi = w2 >> 2, wq = w2 & 3;
    const int head = blockIdx.x >> 6;
    const int q0 = (blockIdx.x & 63) * 64;
    const int qa = q0 + wq * 16 + ln;

    const bf16x8_t qf = *(const bf16x8_t*)(qkvb + (size_t)qa*768 + head*32 + g*8);
    bf16x8_t ones;
    #pragma unroll
    for (int j = 0; j < 8; j++) ones[j] = (short)0x3F80;

    f32x4_t oT0 = {0.f,0.f,0.f,0.f};
    f32x4_t oT1 = {0.f,0.f,0.f,0.f};
    f32x4_t oS  = {0.f,0.f,0.f,0.f};

    const int st = tid & 255;
    const int skey = st >> 2, sc = st & 3;
    const int sd = st >> 3, skc = st & 7;
    const short* kgp = qkvb + 256 + head*32 + sc*8;
    const short* vgp = vt + (size_t)head*131072 + (size_t)sd*4096 + skc*8;
    char* Kg = lds + gi*8192;
    char* Vg = lds + 16384 + gi*8192;
    char* Pw = lds + 32768 + w2*2048;
    const unsigned int* mrow = pmask + (size_t)qa*128;
    const int kswz = (skey & 7) << 4, vswz = (sd & 7) << 4;
    const int pswz = (ln & 7) << 4;

    uint2 mwc;
    {
        const int k0 = gi * 64;
        const bf16x8_t kv = *(const bf16x8_t*)(kgp + (size_t)(k0 + skey)*768);
        *(bf16x8_t*)(Kg + ((skey*64 + sc*16) ^ kswz)) = kv;
        const bf16x8_t vv = *(const bf16x8_t*)(vgp + k0);
        *(bf16x8_t*)(Vg + ((sd*128 + skc*16) ^ vswz)) = vv;
        mwc = *(const uint2*)(mrow + gi*2);
    }

    for (int i = 0; i < 32; ++i) {
        __syncthreads();
        const int cur = i & 1;
        const int tt = 2*i + gi;
        uint2 mwn;
        if (i < 31) {
            const int k0n = (tt + 2) * 64;
            const bf16x8_t kv = *(const bf16x8_t*)(kgp + (size_t)(k0n + skey)*768);
            *(bf16x8_t*)(Kg + (cur^1)*4096 + ((skey*64 + sc*16) ^ kswz)) = kv;
            const bf16x8_t vv = *(const bf16x8_t*)(vgp + k0n);
            *(bf16x8_t*)(Vg + (cur^1)*4096 + ((sd*128 + skc*16) ^ vswz)) = vv;
            mwn = *(const uint2*)(mrow + (tt + 2)*2);
        }
        char* Kb = Kg + cur*4096;
        char* Vb = Vg + cur*4096;

        f32x4_t s[4];
        __builtin_amdgcn_s_setprio(1);
        #pragma unroll
        for (int kt = 0; kt < 4; kt++) {
            const int key = kt*16 + ln;
            const bf16x8_t kf = *(const bf16x8_t*)(Kb + ((key*64 + g*16) ^ ((key & 7) << 4)));
            f32x4_t z = {0.f,0.f,0.f,0.f};
            s[kt] = __builtin_amdgcn_mfma_f32_16x16x32_bf16(kf, qf, z, 0, 0, 0);
        }
        __builtin_amdgcn_s_setprio(0);

        #pragma unroll
        for (int kt = 0; kt < 4; kt++) {
            const unsigned word = (kt < 2) ? mwc.x : mwc.y;
            float p[4];
            #pragma unroll
            for (int r = 0; r < 4; r++) {
                const float e = hw_exp2(s[kt][r] - 17.312340490667562f);
                p[r] = ((word >> ((kt & 1)*16 + g*4 + r)) & 1u) ? e : 0.f;
            }
            uint2 pk;
            pk.x = cvtpk_bf16(p[0], p[1]);
            pk.y = cvtpk_bf16(p[2], p[3]);
            *(uint2*)(Pw + ((ln*128 + kt*32 + g*8) ^ pswz)) = pk;
        }

        __builtin_amdgcn_s_setprio(1);
        #pragma unroll
        for (int kh = 0; kh < 2; kh++) {
            const bf16x8_t pf = *(const bf16x8_t*)(Pw + ((ln*128 + kh*64 + g*16) ^ pswz));
            const bf16x8_t vf0 = *(const bf16x8_t*)(Vb + ((ln*128 + kh*64 + g*16) ^ pswz));
            const bf16x8_t vf1 = *(const bf16x8_t*)(Vb + (((16+ln)*128 + kh*64 + g*16) ^ pswz));
            oT0 = __builtin_amdgcn_mfma_f32_16x16x32_bf16(vf0, pf, oT0, 0, 0, 0);
            oT1 = __builtin_amdgcn_mfma_f32_16x16x32_bf16(vf1, pf, oT1, 0, 0, 0);
            oS  = __builtin_amdgcn_mfma_f32_16x16x32_bf16(ones, pf, oS, 0, 0, 0);
        }
        __builtin_amdgcn_s_setprio(0);
        mwc = mwn;
    }

    float lsum = oS[0];
    __syncthreads();
    *(f32x4_t*)(lds + w2*2048 + l*32)      = oT0;
    *(f32x4_t*)(lds + w2*2048 + l*32 + 16) = oT1;
    ((float*)(lds + 16384))[w2*64 + l] = lsum;
    __syncthreads();
    if (gi == 0) {
        const int pw = w2 + 4;
        const f32x4_t b0 = *(const f32x4_t*)(lds + pw*2048 + l*32);
        const f32x4_t b1 = *(const f32x4_t*)(lds + pw*2048 + l*32 + 16);
        const float lp = ((const float*)(lds + 16384))[pw*64 + l];
        oT0 += b0; oT1 += b1;
        lsum += lp;
        const float inv = 1.0f / fmaxf(lsum, 1e-37f);
        short* op = ob + (size_t)qa * 256 + head*32;
        uint2 w0, w1;
        w0.x = cvtpk_bf16(oT0[0]*inv, oT0[1]*inv);
        w0.y = cvtpk_bf16(oT0[2]*inv, oT0[3]*inv);
        w1.x = cvtpk_bf16(oT1[0]*inv, oT1[1]*inv);
        w1.y = cvtpk_bf16(oT1[2]*inv, oT1[3]*inv);
        *(uint2*)(op + g*4) = w0;
        *(uint2*)(op + 16 + g*4) = w1;
    }
}

// ---------------------------------------------------------------------------
// LayerNorm over 256 dims, one block per row.
// ---------------------------------------------------------------------------
__global__ __launch_bounds__(256)
void ln_k(const float* __restrict__ in, const float* __restrict__ g,
          const float* __restrict__ b, float* __restrict__ out)
{
    const int n = blockIdx.x, t = threadIdx.x;
    const float v = in[(size_t)n * 256 + t];
    float s1 = v, s2 = v * v;
    #pragma unroll
    for (int off = 32; off > 0; off >>= 1) {
        s1 += __shfl_xor(s1, off);
        s2 += __shfl_xor(s2, off);
    }
    __shared__ float r1[4], r2[4];
    const int wv = t >> 6;
    if ((t & 63) == 0) { r1[wv] = s1; r2[wv] = s2; }
    __syncthreads();
    const float t1 = r1[0] + r1[1] + r1[2] + r1[3];
    const float t2 = r2[0] + r2[1] + r2[2] + r2[3];
    const float mu  = t1 * (1.0f / 256.0f);
    const float var = t2 * (1.0f / 256.0f) - mu * mu;
    const float rs  = rsqrtf(var + 1e-5f);
    out[(size_t)n * 256 + t] = (v - mu) * rs * g[t] + b[t];
}

// ---------------------------------------------------------------------------
extern "C" void kernel_launch(void* const* d_in, const int* in_sizes, int n_in,
                              void* d_out, int out_size, void* d_ws, size_t ws_size,
                              hipStream_t stream)
{
    const float* x     = (const float*)d_in[0];
    const int*   ei    = (const int*)  d_in[1];
    const float* eattr = (const float*)d_in[2];
    const int*   mask  = (const int*)  d_in[3];
    const float* W1   = (const float*)d_in[4];
    const float* b1   = (const float*)d_in[5];
    const float* W2   = (const float*)d_in[6];
    const float* b2   = (const float*)d_in[7];
    const float* ipw  = (const float*)d_in[8];
    const float* ipb  = (const float*)d_in[9];
    const float* ow   = (const float*)d_in[10];
    const float* ob_  = (const float*)d_in[11];
    const float* root = (const float*)d_in[12];
    const float* bp   = (const float*)d_in[13];
    const float* ln1g = (const float*)d_in[14];
    const float* ln1b = (const float*)d_in[15];
    const float* ln2g = (const float*)d_in[16];
    const float* ln2b = (const float*)d_in[17];
    const float* linw = (const float*)d_in[18];
    const float* linb = (const float*)d_in[19];
    const int* ei0 = ei;
    const int* ei1 = ei + E_;

    float* ws = (float*)d_ws;
    short* h1b   = (short*)ws;                      // [E,256] bf16
    short* hb    = (short*)(ws + 524288);           // [E,256] bf16
    short* o     = (short*)(ws + 1048576);          // [E,256] bf16 (attn out)
    float* y1    = ws + 1048576;                    //   reuse: o dead after S5
    float* z     = ws + 1572864;                    //   reuse: o dead after S5
    short* qkvb  = (short*)(ws + 2097152);          // [E,768] bf16 (q pre-scaled)
    float* aggr  = ws + 3670016;                    // [N,256] f32
    float* outb  = ws + 4194304;                    // [N,256] f32
    unsigned int* pmask = (unsigned int*)(ws + 4718592);  // [4096][128] bits
    short* vt    = (short*)(ws + 5242896);          // [8][32][4096] bf16
    short* wbuf  = (short*)(ws + 5767184);          // bf16 weights

    dim3 blk(256);
    dim3 blk512(512);
    dim3 blk1024(1024);
    // prep: mask bits + aggr zero + rootT(bf16) + weight f32->bf16
    prep_k<<<dim3(2352), blk, 0, stream>>>(mask, pmask, root, W1, W2, ipw, ow,
                                           linw, wbuf, aggr);

    // S1: h1b = bf16(leakyrelu(cat(x_i,x_j,eattr) @ W1^T + b1))   [MFMA 16w]
    mgemm_k<64,1,true,false,false,false,1><<<dim3(64,4), blk1024, 0, stream>>>(
        nullptr, wbuf + WB1, b1, nullptr, h1b, nullptr, E_, 256, 768, ei0, ei1, x, eattr, 1.0f);
    // S2: hb = bf16(h1b @ W2^T + b2)   [MFMA 16w, bf16 A+B]
    mgemm_k<64,0,false,false,false,true,1><<<dim3(64,4), blk1024, 0, stream>>>(
        h1b, wbuf + WB2, b2, nullptr, hb, nullptr, E_, 256, 256, nullptr, nullptr, nullptr, nullptr, 1.0f);
    // S3: qkvb + vt = hb @ in_proj_w^T + b; q scaled by log2e/sqrt(32)
    mgemm_k<64,0,false,false,false,true,2><<<dim3(64,12), blk1024, 0, stream>>>(
        hb, wbuf + WIPW, ipb, nullptr, qkvb, vt, E_, 768, 256, nullptr, nullptr, nullptr, nullptr,
        0.25503486f);   // log2(e)/sqrt(32)
    // S4: MFMA flash attention -> o (bf16)
    attn_k<<<dim3(512), blk512, 0, stream>>>(qkvb, vt, pmask, o);
    // S5: msg = o @ out_w^T + out_b, scatter-add to aggr   [MFMA 16w]
    mgemm_k<64,0,false,true,false,true,0><<<dim3(64,4), blk1024, 0, stream>>>(
        o, wbuf + WOW, ob_, nullptr, aggr, nullptr, E_, 256, 256, nullptr, ei1, nullptr, nullptr, 1.0f);
    // S6: outb = x @ root + aggr + bias_p   [MFMA BM=32 + exact f32 add]
    mgemm_k<32,0,false,false,true,false,0><<<dim3(64,4), blk512, 0, stream>>>(
        x, wbuf + WROOT, bp, aggr, outb, nullptr, NN_, 256, 256, nullptr, nullptr, nullptr, nullptr, 1.0f);
    // LN1
    ln_k<<<dim3(2048), blk, 0, stream>>>(outb, ln1g, ln1b, y1);
    // F2: z = y1 + y1 @ lin_w^T + lin_b   [MFMA BM=32 + exact f32 residual]
    mgemm_k<32,0,false,false,true,false,0><<<dim3(64,4), blk512, 0, stream>>>(
        y1, wbuf + WLIN, linb, y1, z, nullptr, NN_, 256, 256, nullptr, nullptr, nullptr, nullptr, 1.0f);
    // LN2 -> out
    ln_k<<<dim3(2048), blk, 0, stream>>>(z, ln2g, ln2b, (float*)d_out);
}

// Round 20
// 103.717 us; speedup vs baseline: 1.0410x; 1.0410x over previous
//
#include <hip/hip_runtime.h>
#include <hip/hip_bf16.h>
#include <cstdint>

#define D_   256
#define E_   4096
#define NN_  2048

typedef float f32x4_t __attribute__((ext_vector_type(4)));
typedef short bf16x8_t __attribute__((ext_vector_type(8)));
typedef short bf16x4_t __attribute__((ext_vector_type(4)));

__device__ inline short f2bf(float f) {
    union { float fv; unsigned u; } v; v.fv = f;
    unsigned r = v.u + 0x7fffu + ((v.u >> 16) & 1u);
    return (short)(r >> 16);
}

__device__ inline unsigned cvtpk_bf16(float lo, float hi) {
    unsigned r;
    asm("v_cvt_pk_bf16_f32 %0, %1, %2" : "=v"(r) : "v"(lo), "v"(hi));
    return r;
}

// Raw hardware exp2: v_exp_f32 computes 2^x in one transcendental op.
// (exp2f() is the PRECISE OCML call — cost ~15us/attn, r13 lesson.)
__device__ inline float hw_exp2(float x) {
    float r;
    asm("v_exp_f32 %0, %1" : "=v"(r) : "v"(x));
    return r;
}

// bf16 weight buffer layout (elements):
#define WB1   0
#define WB2   196608
#define WIPW  262144
#define WOW   458752
#define WLIN  524288
#define WROOT 589824

// ---------------------------------------------------------------------------
// bf16 MFMA GEMM, BK=64, 8 waves, BM in {64,32} (r18 validated — r19's
// 16-wave variant REGRESSED: halving per-wave MFMA work per barrier starves
// wave-level ILP; 8 waves is the plateau for this structure).
// B is pre-converted bf16: one 16B load/thread/step, no cvt_pk.
// BM=64: wave = 16x32 (2 frags). BM=32: wave = 16x16 (1 frag) — M=2048 stages.
// ABF16: A bf16. OUT: 0=f32, 1=bf16 (cols<256 scaled by qsc), 2=qkv split.
// SCATTER: f32 atomicAdd via ei1. HASADD: += addsrc (f32, exact).
// ---------------------------------------------------------------------------
template<int BM, int ACT, bool GATHER, bool SCATTER, bool HASADD, bool ABF16, int OUT>
__global__ __launch_bounds__(512)
void mgemm_k(const void* __restrict__ A, const short* __restrict__ Bmb,
             const float* __restrict__ bias, const float* __restrict__ addsrc,
             void* __restrict__ C, short* __restrict__ vtb,
             int M, int N, int K,
             const int* __restrict__ ei0, const int* __restrict__ ei1,
             const float* __restrict__ x, const float* __restrict__ eattr,
             float qsc)
{
    constexpr int ASZ  = BM * 128;
    constexpr int BOFF = 2 * ASZ;
    constexpr int NFR  = (BM == 64) ? 2 : 1;
    __shared__ char lds[BOFF + 16384];
    const int tid = threadIdx.x;
    const int w = tid >> 6, l = tid & 63;
    const int g = l >> 4, ln = l & 15;
    const int wr = (BM == 64) ? (w >> 1) : (w >> 2);
    const int wc = (BM == 64) ? (w & 1)  : (w & 3);
    const int m0 = blockIdx.x * BM, n0 = blockIdx.y * 64;

    const int srow = tid >> 3;
    const int sck  = (tid & 7) * 8;
    const int sswz = (srow & 7) << 4;
    const bool doA = (BM == 64) || (tid < 256);
    int gi1 = 0, gi0 = 0;
    if (GATHER) { gi1 = ei1[m0 + srow]; gi0 = ei0[m0 + srow]; }

    f32x4_t acc[NFR];
    #pragma unroll
    for (int n = 0; n < NFR; n++) acc[n] = f32x4_t{0.f,0.f,0.f,0.f};

    const int nt = K >> 6;
    float4 ga[2];
    bf16x8_t gab, gbb;

    auto loadG = [&](int kk) {
        const int cb = kk + sck;
        if (doA) {
            if (ABF16) {
                gab = *(const bf16x8_t*)((const short*)A + (size_t)(m0 + srow) * K + cb);
            } else {
                const float* src;
                if (GATHER) {
                    if (cb < 256)      src = x + (size_t)gi1 * 256 + cb;
                    else if (cb < 512) src = x + (size_t)gi0 * 256 + (cb - 256);
                    else               src = eattr + (size_t)(m0 + srow) * 256 + (cb - 512);
                } else {
                    src = (const float*)A + (size_t)(m0 + srow) * K + cb;
                }
                ga[0] = *(const float4*)src;
                ga[1] = *(const float4*)(src + 4);
            }
        }
        gbb = *(const bf16x8_t*)(Bmb + (size_t)(n0 + srow) * K + cb);
    };
    auto writeS = [&](int buf) {
        const int off = (srow*128 + sck*2) ^ sswz;
        if (doA) {
            if (ABF16) {
                *(bf16x8_t*)(lds + buf*ASZ + off) = gab;
            } else {
                uint4 pa;
                pa.x = cvtpk_bf16(ga[0].x, ga[0].y); pa.y = cvtpk_bf16(ga[0].z, ga[0].w);
                pa.z = cvtpk_bf16(ga[1].x, ga[1].y); pa.w = cvtpk_bf16(ga[1].z, ga[1].w);
                *(uint4*)(lds + buf*ASZ + off) = pa;
            }
        }
        *(bf16x8_t*)(lds + BOFF + buf*8192 + off) = gbb;
    };

    loadG(0);
    writeS(0);
    __syncthreads();
    int cur = 0;
    for (int t = 0; t < nt; ++t) {
        if (t + 1 < nt) loadG((t + 1) << 6);
        #pragma unroll
        for (int kc = 0; kc < 2; kc++) {
            const int arow = wr*16 + ln;
            const bf16x8_t af = *(const bf16x8_t*)(lds + cur*ASZ +
                    ((arow*128 + kc*64 + g*16) ^ ((arow&7)<<4)));
            #pragma unroll
            for (int n = 0; n < NFR; n++) {
                const int brow = (BM == 64 ? wc*32 + n*16 : wc*16) + ln;
                const bf16x8_t bfr = *(const bf16x8_t*)(lds + BOFF + cur*8192 +
                         ((brow*128 + kc*64 + g*16) ^ ((brow&7)<<4)));
                acc[n] = __builtin_amdgcn_mfma_f32_16x16x32_bf16(af, bfr, acc[n], 0, 0, 0);
            }
        }
        if (t + 1 < nt) writeS(cur ^ 1);
        __syncthreads();
        cur ^= 1;
    }

    #pragma unroll
    for (int n = 0; n < NFR; n++) {
        const int col = n0 + (BM == 64 ? wc*32 + n*16 : wc*16) + ln;
        const float bv = bias[col];
        const int row0 = m0 + wr*16 + g*4;
        float pv[4];
        #pragma unroll
        for (int r = 0; r < 4; r++) {
            float v = acc[n][r] + bv;
            if (ACT == 1) v = v > 0.f ? v : 0.2f * v;
            if (HASADD) v += addsrc[(size_t)(row0 + r) * N + col];
            pv[r] = v;
        }
        if (SCATTER) {
            #pragma unroll
            for (int r = 0; r < 4; r++)
                atomicAdd(&((float*)C)[(size_t)ei1[row0 + r] * 256 + col], pv[r]);
        } else if (OUT == 0) {
            #pragma unroll
            for (int r = 0; r < 4; r++)
                ((float*)C)[(size_t)(row0 + r) * N + col] = pv[r];
        } else if (OUT == 1) {
            #pragma unroll
            for (int r = 0; r < 4; r++)
                ((short*)C)[(size_t)(row0 + r) * N + col] =
                    f2bf((col < 256) ? pv[r] * qsc : pv[r]);
        } else {   // OUT == 2: qkv split
            if (col < 512) {
                #pragma unroll
                for (int r = 0; r < 4; r++)
                    ((short*)C)[(size_t)(row0 + r) * 768 + col] =
                        f2bf((col < 256) ? pv[r] * qsc : pv[r]);
            } else {
                const int hd = (col - 512) >> 5, d = (col - 512) & 31;
                bf16x4_t pk;
                #pragma unroll
                for (int r = 0; r < 4; r++) pk[r] = f2bf(pv[r]);
                *(bf16x4_t*)(vtb + (size_t)hd*131072 + (size_t)d*4096 + row0) = pk;
            }
        }
    }
}

// ---------------------------------------------------------------------------
// Prep: mask bit-pack + aggr zero (0..2047); rootT->bf16 (2048..2063);
// weight f32->bf16 (2064..2351, RNE cvt_pk — bit-identical to per-step cvt).
// ---------------------------------------------------------------------------
__global__ __launch_bounds__(256)
void prep_k(const int* __restrict__ mraw, unsigned int* __restrict__ pm,
            const float* __restrict__ root,
            const float* __restrict__ W1, const float* __restrict__ W2,
            const float* __restrict__ ipw, const float* __restrict__ ow,
            const float* __restrict__ lnw,
            short* __restrict__ wbuf, float* __restrict__ aggr)
{
    __shared__ float T[64][65];
    const int bid = blockIdx.x;
    if (bid < 2048) {
        const int t = bid * 256 + threadIdx.x;
        aggr[t] = 0.f;
        const int row = t >> 7, wb = t & 127;
        unsigned int bits = 0;
        const uint4* p = (const uint4*)(mraw + (size_t)row * 4096 + wb * 32);
        #pragma unroll
        for (int g = 0; g < 8; g++) {
            const uint4 v = p[g];
            if (v.x) bits |= 1u << (g*4+0);
            if (v.y) bits |= 1u << (g*4+1);
            if (v.z) bits |= 1u << (g*4+2);
            if (v.w) bits |= 1u << (g*4+3);
        }
        pm[t] = bits;
    } else if (bid < 2064) {
        const int bt = bid - 2048;
        const int m0 = (bt >> 2) * 64, n0 = (bt & 3) * 64;
        const int r = threadIdx.x >> 6, c = threadIdx.x & 63;
        #pragma unroll
        for (int i = 0; i < 16; i++)
            T[r + i*4][c] = root[(size_t)(m0 + r + i*4) * 256 + n0 + c];
        __syncthreads();
        #pragma unroll
        for (int i = 0; i < 16; i++)
            wbuf[WROOT + (size_t)(n0 + r + i*4) * 256 + m0 + c] = f2bf(T[c][r + i*4]);
    } else {
        const int wid = bid - 2064;
        const float* src; int dst, lw;
        if (wid < 96)       { src = W1;  dst = WB1;  lw = wid; }
        else if (wid < 128) { src = W2;  dst = WB2;  lw = wid - 96; }
        else if (wid < 224) { src = ipw; dst = WIPW; lw = wid - 128; }
        else if (wid < 256) { src = ow;  dst = WOW;  lw = wid - 224; }
        else                { src = lnw; dst = WLIN; lw = wid - 256; }
        const int e0 = (lw * 256 + threadIdx.x) * 8;
        const float4 a = *(const float4*)(src + e0);
        const float4 b = *(const float4*)(src + e0 + 4);
        uint4 p;
        p.x = cvtpk_bf16(a.x, a.y); p.y = cvtpk_bf16(a.z, a.w);
        p.z = cvtpk_bf16(b.x, b.y); p.w = cvtpk_bf16(b.z, b.w);
        *(uint4*)(wbuf + dst + e0) = p;
    }
}

// ---------------------------------------------------------------------------
// MFMA bf16 flash attention (r18 validated 51.7us): swapped QK^T; fixed-shift
// base-2 softmax (q pre-scaled by log2e/sqrt(32), p = hw_exp2(s - 12*log2e));
// split-K x2 strided; dbuf K/V; setprio; mask prefetch; lsum via ones-MFMA;
// additive merge; bf16 output. DO NOT widen split-K (r9/r5 L2 collapse);
// exp2f is OCML (r13).
// ---------------------------------------------------------------------------
__global__ __launch_bounds__(512, 4)
void attn_k(const short* __restrict__ qkvb, const short* __restrict__ vt,
            const unsigned int* __restrict__ pmask, short* __restrict__ ob)
{
    __shared__ char lds[49152];
    const int tid = threadIdx.x;
    const int w2 = tid >> 6, l = tid & 63;
    const int g = l >> 4, ln = l & 15;
    const int gi = w2 >> 2, wq = w2 & 3;
    const int head = blockIdx.x >> 6;
    const int q0 = (blockIdx.x & 63) * 64;
    const int qa = q0 + wq * 16 + ln;

    const bf16x8_t qf = *(const bf16x8_t*)(qkvb + (size_t)qa*768 + head*32 + g*8);
    bf16x8_t ones;
    #pragma unroll
    for (int j = 0; j < 8; j++) ones[j] = (short)0x3F80;

    f32x4_t oT0 = {0.f,0.f,0.f,0.f};
    f32x4_t oT1 = {0.f,0.f,0.f,0.f};
    f32x4_t oS  = {0.f,0.f,0.f,0.f};

    const int st = tid & 255;
    const int skey = st >> 2, sc = st & 3;
    const int sd = st >> 3, skc = st & 7;
    const short* kgp = qkvb + 256 + head*32 + sc*8;
    const short* vgp = vt + (size_t)head*131072 + (size_t)sd*4096 + skc*8;
    char* Kg = lds + gi*8192;
    char* Vg = lds + 16384 + gi*8192;
    char* Pw = lds + 32768 + w2*2048;
    const unsigned int* mrow = pmask + (size_t)qa*128;
    const int kswz = (skey & 7) << 4, vswz = (sd & 7) << 4;
    const int pswz = (ln & 7) << 4;

    uint2 mwc;
    {
        const int k0 = gi * 64;
        const bf16x8_t kv = *(const bf16x8_t*)(kgp + (size_t)(k0 + skey)*768);
        *(bf16x8_t*)(Kg + ((skey*64 + sc*16) ^ kswz)) = kv;
        const bf16x8_t vv = *(const bf16x8_t*)(vgp + k0);
        *(bf16x8_t*)(Vg + ((sd*128 + skc*16) ^ vswz)) = vv;
        mwc = *(const uint2*)(mrow + gi*2);
    }

    for (int i = 0; i < 32; ++i) {
        __syncthreads();
        const int cur = i & 1;
        const int tt = 2*i + gi;
        uint2 mwn;
        if (i < 31) {
            const int k0n = (tt + 2) * 64;
            const bf16x8_t kv = *(const bf16x8_t*)(kgp + (size_t)(k0n + skey)*768);
            *(bf16x8_t*)(Kg + (cur^1)*4096 + ((skey*64 + sc*16) ^ kswz)) = kv;
            const bf16x8_t vv = *(const bf16x8_t*)(vgp + k0n);
            *(bf16x8_t*)(Vg + (cur^1)*4096 + ((sd*128 + skc*16) ^ vswz)) = vv;
            mwn = *(const uint2*)(mrow + (tt + 2)*2);
        }
        char* Kb = Kg + cur*4096;
        char* Vb = Vg + cur*4096;

        f32x4_t s[4];
        __builtin_amdgcn_s_setprio(1);
        #pragma unroll
        for (int kt = 0; kt < 4; kt++) {
            const int key = kt*16 + ln;
            const bf16x8_t kf = *(const bf16x8_t*)(Kb + ((key*64 + g*16) ^ ((key & 7) << 4)));
            f32x4_t z = {0.f,0.f,0.f,0.f};
            s[kt] = __builtin_amdgcn_mfma_f32_16x16x32_bf16(kf, qf, z, 0, 0, 0);
        }
        __builtin_amdgcn_s_setprio(0);

        #pragma unroll
        for (int kt = 0; kt < 4; kt++) {
            const unsigned word = (kt < 2) ? mwc.x : mwc.y;
            float p[4];
            #pragma unroll
            for (int r = 0; r < 4; r++) {
                const float e = hw_exp2(s[kt][r] - 17.312340490667562f);
                p[r] = ((word >> ((kt & 1)*16 + g*4 + r)) & 1u) ? e : 0.f;
            }
            uint2 pk;
            pk.x = cvtpk_bf16(p[0], p[1]);
            pk.y = cvtpk_bf16(p[2], p[3]);
            *(uint2*)(Pw + ((ln*128 + kt*32 + g*8) ^ pswz)) = pk;
        }

        __builtin_amdgcn_s_setprio(1);
        #pragma unroll
        for (int kh = 0; kh < 2; kh++) {
            const bf16x8_t pf = *(const bf16x8_t*)(Pw + ((ln*128 + kh*64 + g*16) ^ pswz));
            const bf16x8_t vf0 = *(const bf16x8_t*)(Vb + ((ln*128 + kh*64 + g*16) ^ pswz));
            const bf16x8_t vf1 = *(const bf16x8_t*)(Vb + (((16+ln)*128 + kh*64 + g*16) ^ pswz));
            oT0 = __builtin_amdgcn_mfma_f32_16x16x32_bf16(vf0, pf, oT0, 0, 0, 0);
            oT1 = __builtin_amdgcn_mfma_f32_16x16x32_bf16(vf1, pf, oT1, 0, 0, 0);
            oS  = __builtin_amdgcn_mfma_f32_16x16x32_bf16(ones, pf, oS, 0, 0, 0);
        }
        __builtin_amdgcn_s_setprio(0);
        mwc = mwn;
    }

    float lsum = oS[0];
    __syncthreads();
    *(f32x4_t*)(lds + w2*2048 + l*32)      = oT0;
    *(f32x4_t*)(lds + w2*2048 + l*32 + 16) = oT1;
    ((float*)(lds + 16384))[w2*64 + l] = lsum;
    __syncthreads();
    if (gi == 0) {
        const int pw = w2 + 4;
        const f32x4_t b0 = *(const f32x4_t*)(lds + pw*2048 + l*32);
        const f32x4_t b1 = *(const f32x4_t*)(lds + pw*2048 + l*32 + 16);
        const float lp = ((const float*)(lds + 16384))[pw*64 + l];
        oT0 += b0; oT1 += b1;
        lsum += lp;
        const float inv = 1.0f / fmaxf(lsum, 1e-37f);
        short* op = ob + (size_t)qa * 256 + head*32;
        uint2 w0, w1;
        w0.x = cvtpk_bf16(oT0[0]*inv, oT0[1]*inv);
        w0.y = cvtpk_bf16(oT0[2]*inv, oT0[3]*inv);
        w1.x = cvtpk_bf16(oT1[0]*inv, oT1[1]*inv);
        w1.y = cvtpk_bf16(oT1[2]*inv, oT1[3]*inv);
        *(uint2*)(op + g*4) = w0;
        *(uint2*)(op + 16 + g*4) = w1;
    }
}

// ---------------------------------------------------------------------------
// LayerNorm over 256 dims, one block per row.
// ---------------------------------------------------------------------------
__global__ __launch_bounds__(256)
void ln_k(const float* __restrict__ in, const float* __restrict__ g,
          const float* __restrict__ b, float* __restrict__ out)
{
    const int n = blockIdx.x, t = threadIdx.x;
    const float v = in[(size_t)n * 256 + t];
    float s1 = v, s2 = v * v;
    #pragma unroll
    for (int off = 32; off > 0; off >>= 1) {
        s1 += __shfl_xor(s1, off);
        s2 += __shfl_xor(s2, off);
    }
    __shared__ float r1[4], r2[4];
    const int wv = t >> 6;
    if ((t & 63) == 0) { r1[wv] = s1; r2[wv] = s2; }
    __syncthreads();
    const float t1 = r1[0] + r1[1] + r1[2] + r1[3];
    const float t2 = r2[0] + r2[1] + r2[2] + r2[3];
    const float mu  = t1 * (1.0f / 256.0f);
    const float var = t2 * (1.0f / 256.0f) - mu * mu;
    const float rs  = rsqrtf(var + 1e-5f);
    out[(size_t)n * 256 + t] = (v - mu) * rs * g[t] + b[t];
}

// ---------------------------------------------------------------------------
extern "C" void kernel_launch(void* const* d_in, const int* in_sizes, int n_in,
                              void* d_out, int out_size, void* d_ws, size_t ws_size,
                              hipStream_t stream)
{
    const float* x     = (const float*)d_in[0];
    const int*   ei    = (const int*)  d_in[1];
    const float* eattr = (const float*)d_in[2];
    const int*   mask  = (const int*)  d_in[3];
    const float* W1   = (const float*)d_in[4];
    const float* b1   = (const float*)d_in[5];
    const float* W2   = (const float*)d_in[6];
    const float* b2   = (const float*)d_in[7];
    const float* ipw  = (const float*)d_in[8];
    const float* ipb  = (const float*)d_in[9];
    const float* ow   = (const float*)d_in[10];
    const float* ob_  = (const float*)d_in[11];
    const float* root = (const float*)d_in[12];
    const float* bp   = (const float*)d_in[13];
    const float* ln1g = (const float*)d_in[14];
    const float* ln1b = (const float*)d_in[15];
    const float* ln2g = (const float*)d_in[16];
    const float* ln2b = (const float*)d_in[17];
    const float* linw = (const float*)d_in[18];
    const float* linb = (const float*)d_in[19];
    const int* ei0 = ei;
    const int* ei1 = ei + E_;

    float* ws = (float*)d_ws;
    short* h1b   = (short*)ws;                      // [E,256] bf16
    short* hb    = (short*)(ws + 524288);           // [E,256] bf16
    short* o     = (short*)(ws + 1048576);          // [E,256] bf16 (attn out)
    float* y1    = ws + 1048576;                    //   reuse: o dead after S5
    float* z     = ws + 1572864;                    //   reuse: o dead after S5
    short* qkvb  = (short*)(ws + 2097152);          // [E,768] bf16 (q pre-scaled)
    float* aggr  = ws + 3670016;                    // [N,256] f32
    float* outb  = ws + 4194304;                    // [N,256] f32
    unsigned int* pmask = (unsigned int*)(ws + 4718592);  // [4096][128] bits
    short* vt    = (short*)(ws + 5242896);          // [8][32][4096] bf16
    short* wbuf  = (short*)(ws + 5767184);          // bf16 weights

    dim3 blk(256);
    dim3 blk512(512);
    // prep: mask bits + aggr zero + rootT(bf16) + weight f32->bf16
    prep_k<<<dim3(2352), blk, 0, stream>>>(mask, pmask, root, W1, W2, ipw, ow,
                                           linw, wbuf, aggr);

    // S1: h1b = bf16(leakyrelu(cat(x_i,x_j,eattr) @ W1^T + b1))   [MFMA]
    mgemm_k<64,1,true,false,false,false,1><<<dim3(64,4), blk512, 0, stream>>>(
        nullptr, wbuf + WB1, b1, nullptr, h1b, nullptr, E_, 256, 768, ei0, ei1, x, eattr, 1.0f);
    // S2: hb = bf16(h1b @ W2^T + b2)   [MFMA, bf16 A+B]
    mgemm_k<64,0,false,false,false,true,1><<<dim3(64,4), blk512, 0, stream>>>(
        h1b, wbuf + WB2, b2, nullptr, hb, nullptr, E_, 256, 256, nullptr, nullptr, nullptr, nullptr, 1.0f);
    // S3: qkvb + vt = hb @ in_proj_w^T + b; q scaled by log2e/sqrt(32);
    //     V columns written transposed into vt
    mgemm_k<64,0,false,false,false,true,2><<<dim3(64,12), blk512, 0, stream>>>(
        hb, wbuf + WIPW, ipb, nullptr, qkvb, vt, E_, 768, 256, nullptr, nullptr, nullptr, nullptr,
        0.25503486f);   // log2(e)/sqrt(32)
    // S4: MFMA flash attention -> o (bf16)
    attn_k<<<dim3(512), blk512, 0, stream>>>(qkvb, vt, pmask, o);
    // S5: msg = o @ out_w^T + out_b, scatter-add to aggr   [MFMA, bf16 A+B]
    mgemm_k<64,0,false,true,false,true,0><<<dim3(64,4), blk512, 0, stream>>>(
        o, wbuf + WOW, ob_, nullptr, aggr, nullptr, E_, 256, 256, nullptr, ei1, nullptr, nullptr, 1.0f);
    // S6: outb = x @ root + aggr + bias_p   [MFMA BM=32 + exact f32 add]
    mgemm_k<32,0,false,false,true,false,0><<<dim3(64,4), blk512, 0, stream>>>(
        x, wbuf + WROOT, bp, aggr, outb, nullptr, NN_, 256, 256, nullptr, nullptr, nullptr, nullptr, 1.0f);
    // LN1
    ln_k<<<dim3(2048), blk, 0, stream>>>(outb, ln1g, ln1b, y1);
    // F2: z = y1 + y1 @ lin_w^T + lin_b   [MFMA BM=32 + exact f32 residual]
    mgemm_k<32,0,false,false,true,false,0><<<dim3(64,4), blk512, 0, stream>>>(
        y1, wbuf + WLIN, linb, y1, z, nullptr, NN_, 256, 256, nullptr, nullptr, nullptr, nullptr, 1.0f);
    // LN2 -> out
    ln_k<<<dim3(2048), blk, 0, stream>>>(z, ln2g, ln2b, (float*)d_out);
}